// Round 15
// baseline (315.389 us; speedup 1.0000x reference)
//
#include <hip/hip_runtime.h>
#include <math.h>
#include <stdint.h>

// Problem constants
#define BB 4
#define HH 64
#define WW2 64
#define DM 96
#define DN 192
#define KK 4
#define NN 16
#define RR 6
#define LL 4096
#define RN 38   // R + 2N

#define LOG2E 1.4426950408889634f
#define LN2   0.6931471805599453f

// Workspace layout (4-byte units). Peak = 24,923,456 floats = 99.69 MB.
#define OFF_WDB      0           // u32[768] packed Wd sign bits + float[768] sd at +768
#define OFF_WCS      4608        // u32[192*56] packed conv weights
#define OFF_WAUX     15360       // int[192*8] conv border corrections
#define OFF_WSC      16896       // float[192] conv scale
#define OFF_WBIB     17088       // u32[384*3] packed W_in sign bits
#define OFF_WOUTB    18240       // u32[96*6] packed W_out sign bits
#define OFF_WLBB     18816       // u32[152*6] packed Wl sign bits
// shared scratch pool (lifetime-disjoint): 393216 words @ 19728
#define OFF_XBP      19728       // u32[4*6*4356] conv input bit planes
#define OFF_PXS      19728       // u32[16*24576] packed sign(xs) flat
#define OFF_SSUM     19728       // float[64*3072] chunk delta sums
#define OFF_XC       412992      // float[3145728] xp (B,Dn,L); then y [b][d][l] (comb out)
#define OFF_ZS       3558720     // float[3145728] silu(z) (B,L,Dn)
#define OFF_XCONV    6704448     // float[3145728] conv out (B,Dn,L); reused as hend/h0
#define OFF_XS       9850176     // float[12582912] scan input; scan_c overwrites with per-k y
#define OFF_XDBL     22433088    // float[16*38*4096] x_dbl (B,K,38,L)
#define OFF_HEND     OFF_XCONV

#define PLANE 4356   // 66*66

__device__ __forceinline__ float fsign(float v) {
  return (v > 0.f) ? 1.f : ((v < 0.f) ? -1.f : 0.f);
}
__device__ __forceinline__ float softplusf(float v) {
  return fmaxf(v, 0.f) + LN2 * log2f(1.f + exp2f(-fabsf(v) * LOG2E));
}
__device__ __forceinline__ float siluf(float v) {
  return v / (1.f + expf(-v));
}
__device__ __forceinline__ float waveAllSum(float s) {
  #pragma unroll
  for (int off = 32; off; off >>= 1) s += __shfl_xor(s, off, 64);
  return s;
}

// ---------------- prep: pack all sign weights + zero conv-plane borders ----------------
__global__ __launch_bounds__(64) void k_prep(
    const float* __restrict__ W_in, const float* __restrict__ s_in,
    const float* __restrict__ W_out, const float* __restrict__ s_out,
    const float* __restrict__ Wl, const float* __restrict__ sl,
    const float* __restrict__ Wd, const float* __restrict__ sd,
    const float* __restrict__ convW, float* __restrict__ ws) {
  __shared__ float srow[1728];
  int r = blockIdx.x, lane = threadIdx.x;
  if (r < 384) {
    const float* row = W_in + r * DM;
    float s = 0.f;
    for (int c = lane; c < DM; c += 64) s += row[c];
    s = waveAllSum(s);
    float mean = s / (float)DM;
    if (lane < 3) {
      uint32_t wv = 0;
      #pragma unroll
      for (int i = 0; i < 32; ++i) wv |= (row[lane * 32 + i] - mean > 0.f ? 1u : 0u) << i;
      ((uint32_t*)(ws + OFF_WBIB))[r * 3 + lane] = wv;
    }
  } else if (r < 480) {
    int m = r - 384;
    const float* row = W_out + m * DN;
    float s = 0.f;
    for (int c = lane; c < DN; c += 64) s += row[c];
    s = waveAllSum(s);
    float mean = s / (float)DN;
    if (lane < 6) {
      uint32_t wv = 0;
      #pragma unroll
      for (int i = 0; i < 32; ++i) wv |= (row[lane * 32 + i] - mean > 0.f ? 1u : 0u) << i;
      ((uint32_t*)(ws + OFF_WOUTB))[m * 6 + lane] = wv;
    }
  } else if (r < 632) {
    int idx = r - 480;
    const float* row = Wl + idx * DN;
    float s = 0.f;
    for (int c = lane; c < DN; c += 64) s += row[c];
    s = waveAllSum(s);
    float mean = s / (float)DN;
    if (lane < 6) {
      uint32_t wv = 0;
      #pragma unroll
      for (int i = 0; i < 32; ++i) wv |= (row[lane * 32 + i] - mean > 0.f ? 1u : 0u) << i;
      ((uint32_t*)(ws + OFF_WLBB))[idx * 6 + lane] = wv;
    }
  } else if (r < 1400) {
    int idx = r - 632;
    const float* row = Wd + idx * RR;
    float s = (lane < RR) ? row[lane] : 0.f;
    s = waveAllSum(s);
    float mean = s / (float)RR;
    unsigned long long mb = __ballot((lane < RR) && (row[lane] - mean > 0.f));
    if (lane == 0) {
      ((uint32_t*)(ws + OFF_WDB))[idx] = (uint32_t)mb & 0x3Fu;
      (ws + OFF_WDB)[768 + idx] = sd[idx];
    }
  } else if (r < 1592) {
    int o = r - 1400;
    const float* row = convW + o * 1728;
    float s = 0.f;
    for (int j = lane; j < 1728; j += 64) {
      float v = row[j];
      srow[j] = v;
      s += fabsf(v);
    }
    s = waveAllSum(s);
    __syncthreads();
    float sc = s / 1728.f;
    uint32_t* wb = (uint32_t*)(ws + OFF_WCS);
    int* aux = (int*)(ws + OFF_WAUX);
    float* scf = ws + OFF_WSC;
    uint32_t word = 0;
    if (lane < 54) {
      int cw = lane / 9, tap = lane % 9;
      #pragma unroll
      for (int i = 0; i < 32; ++i)
        word |= (srow[(cw * 32 + i) * 9 + tap] > 0.f ? 1u : 0u) << i;
      wb[o * 56 + lane] = word;
    } else if (lane < 56) {
      wb[o * 56 + lane] = 0u;
    }
    int pc = (lane < 54) ? 2 * (int)__popc(word) - 32 : 0;
    int tapid = lane % 9;
    int wst = 0;
    #pragma unroll
    for (int cw = 0; cw < 6; ++cw) wst += __shfl(pc, cw * 9 + tapid, 64);
    int w_t[9];
    #pragma unroll
    for (int t9 = 0; t9 < 9; ++t9) w_t[t9] = __shfl(wst, t9, 64);
    if (lane == 0) {
      aux[o * 8 + 0] = w_t[0] + w_t[3] + w_t[6];
      aux[o * 8 + 1] = w_t[2] + w_t[5] + w_t[8];
      aux[o * 8 + 2] = w_t[0] + w_t[1] + w_t[2];
      aux[o * 8 + 3] = w_t[6] + w_t[7] + w_t[8];
      aux[o * 8 + 4] = w_t[0];
      aux[o * 8 + 5] = w_t[2];
      aux[o * 8 + 6] = w_t[6];
      aux[o * 8 + 7] = w_t[8];
      scf[o] = sc;
    }
  } else {
    // zero the border of one conv bit-plane (24 planes)
    int p = r - 1592;
    uint32_t* plane = (uint32_t*)(ws + OFF_XBP) + (size_t)p * PLANE;
    for (int i = lane; i < 66; i += 64) {
      plane[i] = 0u;                    // top row
      plane[65 * 66 + i] = 0u;          // bottom row
    }
    for (int i = lane; i < 64; i += 64) {
      plane[(i + 1) * 66] = 0u;         // left col
      plane[(i + 1) * 66 + 65] = 0u;    // right col
    }
  }
}

// ---------------- input bilinear via XOR-popcount + fused conv-input bit-pack ----------------
__global__ __launch_bounds__(384) void k_bilin_in(
    const float* __restrict__ x, const float* __restrict__ b_in,
    const float* __restrict__ s_in, const float* __restrict__ move0,
    const float* __restrict__ ws, float* __restrict__ xc, float* __restrict__ zs,
    uint32_t* __restrict__ xb) {
  __shared__ uint32_t spx[16 * 3];
  __shared__ float sxz[384 * 17];
  __shared__ float smv[DN];
  int p0 = blockIdx.x * 16;
  if (threadIdx.x < 48) {
    int pix = threadIdx.x / 3, wd = threadIdx.x % 3;
    const float* base = x + (size_t)(p0 + pix) * DM + wd * 32;
    uint32_t wv = 0;
    #pragma unroll
    for (int i = 0; i < 32; ++i) wv |= (base[i] > 0.f ? 1u : 0u) << i;
    spx[pix * 3 + wd] = wv;
  }
  if (threadIdx.x < DN) smv[threadIdx.x] = move0[threadIdx.x];
  __syncthreads();
  int o = threadIdx.x;
  uint32_t w0, w1, w2;
  {
    const uint32_t* wb = (const uint32_t*)(ws + OFF_WBIB) + o * 3;
    w0 = wb[0]; w1 = wb[1]; w2 = wb[2];
  }
  float bias = b_in[o], sc = s_in[o];
  #pragma unroll
  for (int pix = 0; pix < 16; ++pix) {
    int P = (int)__popc(spx[pix * 3 + 0] ^ w0) + (int)__popc(spx[pix * 3 + 1] ^ w1) +
            (int)__popc(spx[pix * 3 + 2] ^ w2);
    sxz[o * 17 + pix] = bias + sc * (float)(DM - 2 * P);
  }
  __syncthreads();
  int b = p0 >> 12, l0 = p0 & 4095;
  for (int f = threadIdx.x; f < DN * 16; f += 384) {
    int od = f >> 4, pix = f & 15;
    xc[((size_t)(b * DN + od)) * LL + l0 + pix] = sxz[od * 17 + pix];
  }
  for (int f = threadIdx.x; f < DN * 16; f += 384) {
    int pix = f / DN, oz = f - pix * DN;
    zs[(size_t)(p0 + pix) * DN + oz] = siluf(sxz[(DN + oz) * 17 + pix]);
  }
  if (threadIdx.x < 96) {
    int pix = threadIdx.x / 6, cw = threadIdx.x % 6;
    uint32_t wv = 0;
    #pragma unroll
    for (int i = 0; i < 32; ++i) {
      int dch = cw * 32 + i;
      wv |= ((sxz[dch * 17 + pix] + smv[dch] > 0.f) ? 1u : 0u) << i;
    }
    int l = l0 + pix, h = l >> 6, w = l & 63;
    uint32_t* plane = xb + (size_t)(b * 6 + cw) * PLANE;
    plane[(h + 1) * 66 + 1 + w] = wv;
  }
}

// ---------------- XNOR-popcount binary 3x3 conv + RPReLU + residual + SiLU ----------------
__global__ __launch_bounds__(256) void k_conv(
    const uint32_t* __restrict__ xb, const float* __restrict__ xc,
    const uint32_t* __restrict__ wbits, const int* __restrict__ aux,
    const float* __restrict__ scf, const float* __restrict__ conv_b,
    const float* __restrict__ rp_b0, const float* __restrict__ prelu_a,
    const float* __restrict__ rp_b1, float* __restrict__ xconv) {
  int og = blockIdx.x & 3;
  int stripe = (blockIdx.x >> 2) & 15;
  int b = blockIdx.x >> 6;
  int w = threadIdx.x & 63, r = threadIdx.x >> 6;
  int h = stripe * 4 + r;

  __shared__ uint32_t swb[48 * 56];
  __shared__ int saux[48 * 8];
  __shared__ float sconst[48 * 4];
  for (int i = threadIdx.x; i < 48 * 56; i += 256) swb[i] = wbits[og * (48 * 56) + i];
  for (int i = threadIdx.x; i < 48 * 8; i += 256) saux[i] = aux[og * (48 * 8) + i];
  if (threadIdx.x < 48) {
    int o = og * 48 + threadIdx.x;
    sconst[threadIdx.x * 4 + 0] = scf[o];
    sconst[threadIdx.x * 4 + 1] = conv_b[o] + rp_b0[o];
    sconst[threadIdx.x * 4 + 2] = prelu_a[o];
    sconst[threadIdx.x * 4 + 3] = rp_b1[o];
  }

  uint32_t xw[6][9];
  const uint32_t* xpb = xb + (size_t)b * 6 * PLANE;
  #pragma unroll
  for (int cw = 0; cw < 6; ++cw) {
    const uint32_t* plane = xpb + cw * PLANE + (h + 1) * 66 + (w + 1);
    #pragma unroll
    for (int dy = 0; dy < 3; ++dy) {
      #pragma unroll
      for (int dx = 0; dx < 3; ++dx)
        xw[cw][dy * 3 + dx] = plane[(dy - 1) * 66 + (dx - 1)];
    }
  }
  bool isL = (w == 0), isR = (w == 63);
  bool isT = (h == 0), isB = (h == 63);
  const float* xcp = xc + ((size_t)(b * DN + og * 48)) * LL + h * 64 + w;
  float* xop = xconv + ((size_t)(b * DN + og * 48)) * LL + h * 64 + w;
  __syncthreads();

  #pragma unroll 1
  for (int oc = 0; oc < 48; ++oc) {
    const uint32_t* wp = &swb[oc * 56];
    int P = 0;
    #pragma unroll
    for (int cw = 0; cw < 6; ++cw) {
      int pp = 0;
      #pragma unroll
      for (int t = 0; t < 9; ++t) pp += (int)__popc(wp[cw * 9 + t] ^ xw[cw][t]);
      P += pp;
    }
    int corr = isL ? saux[oc * 8 + 0] : (isR ? saux[oc * 8 + 1] : 0);
    if (isT) {
      corr += saux[oc * 8 + 2];
      if (isL) corr -= saux[oc * 8 + 4];
      if (isR) corr -= saux[oc * 8 + 5];
    }
    if (isB) {
      corr += saux[oc * 8 + 3];
      if (isL) corr -= saux[oc * 8 + 6];
      if (isR) corr -= saux[oc * 8 + 7];
    }
    float acc = sconst[oc * 4 + 0] * (float)(1728 - 2 * P + corr);
    float t = acc + sconst[oc * 4 + 1];
    t = (t >= 0.f) ? t : sconst[oc * 4 + 2] * t;
    t += sconst[oc * 4 + 3] + *xcp;
    *xop = siluf(t);
    xcp += LL; xop += LL;
  }
}

// ---------------- build xs: LDS-tiled 4-direction expand + ballot bit-pack ----------------
__global__ __launch_bounds__(256) void k_build_xs(const float* __restrict__ xconv,
                                                  float* __restrict__ xs,
                                                  uint32_t* __restrict__ pxs) {
  __shared__ float tile[64][65];
  int bd = blockIdx.x;
  int b = bd / DN, d = bd % DN;
  const float* img = xconv + (size_t)bd * LL;
  for (int i = threadIdx.x; i < LL; i += 256)
    tile[i >> 6][i & 63] = img[i];
  __syncthreads();
  int lane = threadIdx.x & 63;
  #pragma unroll
  for (int k = 0; k < 4; ++k) {
    size_t base = ((size_t)((b * KK + k) * DN + d)) * LL;
    for (int j = threadIdx.x; j < LL; j += 256) {
      float v;
      if (k == 0)      v = tile[j >> 6][j & 63];
      else if (k == 1) v = tile[j & 63][j >> 6];
      else if (k == 2) { int t2 = 4095 - j; v = tile[t2 >> 6][t2 & 63]; }
      else             { int t2 = 4095 - j; v = tile[t2 & 63][t2 >> 6]; }
      xs[base + j] = v;
      unsigned long long m = __ballot(v > 0.f);
      if (lane == 0)       pxs[(base + j) >> 5] = (uint32_t)m;
      else if (lane == 32) pxs[(base + j) >> 5] = (uint32_t)(m >> 32);
    }
  }
}

// ---------------- x_dbl via XOR-popcount ----------------
__global__ __launch_bounds__(256) void k_xdbl(
    const uint32_t* __restrict__ pxs, const float* __restrict__ ws,
    const float* __restrict__ bl, const float* __restrict__ sl,
    float* __restrict__ xdbl) {
  int bk = blockIdx.x >> 4;
  int l = ((blockIdx.x & 15) << 8) + threadIdx.x;
  int k = bk & 3;
  __shared__ uint32_t swl[RN * 6];
  __shared__ float sbias[RN], ssc[RN];
  if (threadIdx.x < RN * 6) swl[threadIdx.x] = ((const uint32_t*)(ws + OFF_WLBB))[k * RN * 6 + threadIdx.x];
  if (threadIdx.x < RN) {
    sbias[threadIdx.x] = bl[k * RN + threadIdx.x];
    ssc[threadIdx.x] = sl[k * RN + threadIdx.x];
  }
  uint32_t xb[6];
  const uint32_t* pp = pxs + (size_t)bk * 24576 + (size_t)l * 6;
  #pragma unroll
  for (int j = 0; j < 6; ++j) xb[j] = pp[j];
  __syncthreads();
  float* xo = xdbl + (size_t)bk * (RN * LL) + l;
  #pragma unroll 1
  for (int o = 0; o < RN; ++o) {
    int P = 0;
    #pragma unroll
    for (int j = 0; j < 6; ++j) P += (int)__popc(xb[j] ^ swl[o * 6 + j]);
    xo[(size_t)o * LL] = sbias[o] + ssc[o] * (float)(DN - 2 * P);
  }
}

// power ladder: a[n] = r^(n+1), 14 mults, depth 4
__device__ __forceinline__ void rpowers(float r, float* a) {
  float r2 = r * r, r3 = r2 * r, r4 = r2 * r2, r8 = r4 * r4;
  a[0] = r;       a[1] = r2;      a[2] = r3;      a[3] = r4;
  a[4] = r4 * r;  a[5] = r4 * r2; a[6] = r4 * r3; a[7] = r8;
  a[8] = r8 * r;  a[9] = r8 * r2; a[10] = r8 * r3; a[11] = r8 * r4;
  a[12] = r8 * a[4]; a[13] = r8 * a[5]; a[14] = r8 * a[6]; a[15] = r8 * r8;
}

// ---------------- scan pass A ----------------
__global__ __launch_bounds__(192) void k_scan_a(
    const float* __restrict__ xs, const float* __restrict__ xdbl,
    const float* __restrict__ ws, const float* __restrict__ bd,
    const float* __restrict__ dt_bias, const float* __restrict__ A_logs,
    float* __restrict__ hend, float* __restrict__ Ssum) {
  int c = blockIdx.x & 63;
  int bk = blockIdx.x >> 6;
  int k = bk & 3;
  int d = threadIdx.x;
  int t0 = c << 6;
  __shared__ uint32_t sdtm[64];
  __shared__ float4 sB4[256];
  __shared__ float sDV[7 * 192], sR[7 * 192];
  float* sBf = (float*)sB4;
  const float* dtbase = xdbl + (size_t)bk * (RN * LL);
  if (d < 64) {
    const float2* p2 = (const float2*)(dtbase + t0 * 6 + d * 6);
    float2 a = p2[0], bb = p2[1], cc = p2[2];
    uint32_t m = (a.x > 0.f ? 1u : 0u) | (a.y > 0.f ? 2u : 0u) |
                 (bb.x > 0.f ? 4u : 0u) | (bb.y > 0.f ? 8u : 0u) |
                 (cc.x > 0.f ? 16u : 0u) | (cc.y > 0.f ? 32u : 0u);
    sdtm[d] = m;
  }
  {
    const float4* Bp = (const float4*)(xdbl + ((size_t)bk * RN + RR) * LL);
    for (int i = d; i < 256; i += 192) {
      int n = i >> 4, j = i & 15;
      float4 v = Bp[n * 1024 + (t0 >> 2) + j];
      sBf[(4 * j + 0) * 16 + n] = v.x;
      sBf[(4 * j + 1) * 16 + n] = v.y;
      sBf[(4 * j + 2) * 16 + n] = v.z;
      sBf[(4 * j + 3) * 16 + n] = v.w;
    }
  }
  uint32_t w6 = ((const uint32_t*)(ws + OFF_WDB))[k * DN + d];
  float sdv = (ws + OFF_WDB)[768 + k * DN + d];
  float biasd = bd[k * DN + d] + dt_bias[k * DN + d];
  #pragma unroll
  for (int pc = 0; pc < 7; ++pc) {
    float dv = softplusf(biasd + sdv * (float)(RR - 2 * pc));
    sDV[pc * 192 + d] = dv;
    sR[pc * 192 + d] = exp2f(-dv * LOG2E);
  }
  float Araw[16];
  bool fok = true;
  {
    const float* ap = A_logs + (k * DN + d) * NN;
    #pragma unroll
    for (int n = 0; n < NN; ++n) {
      Araw[n] = -expf(ap[n]);
      fok = fok && (fabsf(Araw[n] + (float)(n + 1)) < 1e-3f);
    }
  }
  bool fastpath = (__ballot(fok) == ~0ull);
  float h[16];
  #pragma unroll
  for (int n = 0; n < NN; ++n) h[n] = 0.f;
  float S = 0.f;
  const float* up = xs + ((size_t)bk * DN + d) * LL + t0;
  __syncthreads();
  if (fastpath) {
    #pragma unroll 1
    for (int tt = 0; tt < 16; ++tt) {
      float4 u4 = *(const float4*)(up + 4 * tt);
      #pragma unroll
      for (int q = 0; q < 4; ++q) {
        int t = 4 * tt + q;
        float uv = (q == 0) ? u4.x : (q == 1) ? u4.y : (q == 2) ? u4.z : u4.w;
        int pc = (int)__popc(sdtm[t] ^ w6);
        float dv = sDV[pc * 192 + d];
        float rr = sR[pc * 192 + d];
        S += dv;
        float du = dv * uv;
        float a[16];
        rpowers(rr, a);
        #pragma unroll
        for (int g = 0; g < 4; ++g) {
          float4 bv = sB4[t * 4 + g];
          h[4 * g + 0] = a[4 * g + 0] * h[4 * g + 0] + du * bv.x;
          h[4 * g + 1] = a[4 * g + 1] * h[4 * g + 1] + du * bv.y;
          h[4 * g + 2] = a[4 * g + 2] * h[4 * g + 2] + du * bv.z;
          h[4 * g + 3] = a[4 * g + 3] * h[4 * g + 3] + du * bv.w;
        }
      }
    }
  } else {
    float An[16];
    #pragma unroll
    for (int n = 0; n < NN; ++n) An[n] = Araw[n] * LOG2E;
    #pragma unroll 1
    for (int tt = 0; tt < 16; ++tt) {
      float4 u4 = *(const float4*)(up + 4 * tt);
      #pragma unroll
      for (int q = 0; q < 4; ++q) {
        int t = 4 * tt + q;
        float uv = (q == 0) ? u4.x : (q == 1) ? u4.y : (q == 2) ? u4.z : u4.w;
        int pc = (int)__popc(sdtm[t] ^ w6);
        float dv = sDV[pc * 192 + d];
        S += dv;
        float du = dv * uv;
        #pragma unroll
        for (int g = 0; g < 4; ++g) {
          float4 bv = sB4[t * 4 + g];
          float a0 = exp2f(dv * An[4 * g + 0]);
          float a1 = exp2f(dv * An[4 * g + 1]);
          float a2 = exp2f(dv * An[4 * g + 2]);
          float a3 = exp2f(dv * An[4 * g + 3]);
          h[4 * g + 0] = a0 * h[4 * g + 0] + du * bv.x;
          h[4 * g + 1] = a1 * h[4 * g + 1] + du * bv.y;
          h[4 * g + 2] = a2 * h[4 * g + 2] + du * bv.z;
          h[4 * g + 3] = a3 * h[4 * g + 3] + du * bv.w;
        }
      }
    }
  }
  float* hp = hend + (size_t)c * 49152 + (size_t)(bk * DN + d) * 16;
  #pragma unroll
  for (int n = 0; n < NN; n += 4)
    *(float4*)(hp + n) = make_float4(h[n], h[n + 1], h[n + 2], h[n + 3]);
  Ssum[c * 3072 + bk * DN + d] = S;
}

// ---------------- scan pass B ----------------
__global__ __launch_bounds__(256) void k_scan_b(
    const float* __restrict__ A_logs, const float* __restrict__ Ssum,
    float* __restrict__ hend) {
  int tid = blockIdx.x * 256 + threadIdx.x;
  int bkd = tid >> 4, n = tid & 15;
  int bk = bkd / DN, d = bkd - bk * DN;
  int k = bk & 3;
  float An2 = -expf(A_logs[(k * DN + d) * NN + n]) * LOG2E;
  float h = 0.f;
  float Sc = Ssum[bkd];
  float he = hend[tid];
  #pragma unroll 1
  for (int c = 0; c < 64; ++c) {
    float Sn = 0.f, hn = 0.f;
    if (c < 63) {
      Sn = Ssum[(c + 1) * 3072 + bkd];
      hn = hend[(size_t)(c + 1) * 49152 + tid];
    }
    hend[(size_t)c * 49152 + tid] = h;
    h = exp2f(An2 * Sc) * h + he;
    Sc = Sn; he = hn;
  }
}

// ---------------- scan pass C: no atomics, y in place into xs ----------------
__global__ __launch_bounds__(192) void k_scan_c(
    float* __restrict__ xs, const float* __restrict__ xdbl,
    const float* __restrict__ ws, const float* __restrict__ bd,
    const float* __restrict__ dt_bias, const float* __restrict__ A_logs,
    const float* __restrict__ Ds, const float* __restrict__ h0buf) {
  int c = blockIdx.x & 63;
  int bk = blockIdx.x >> 6;
  int k = bk & 3;
  int d = threadIdx.x;
  int t0 = c << 6;
  __shared__ uint32_t sdtm[64];
  __shared__ float4 sB4[256];
  __shared__ float4 sC4[256];
  __shared__ float sDV[7 * 192], sR[7 * 192];
  __shared__ float ytile[192 * 17];
  float* sBf = (float*)sB4;
  float* sCf = (float*)sC4;
  const float* dtbase = xdbl + (size_t)bk * (RN * LL);
  if (d < 64) {
    const float2* p2 = (const float2*)(dtbase + t0 * 6 + d * 6);
    float2 a = p2[0], bb = p2[1], cc = p2[2];
    uint32_t m = (a.x > 0.f ? 1u : 0u) | (a.y > 0.f ? 2u : 0u) |
                 (bb.x > 0.f ? 4u : 0u) | (bb.y > 0.f ? 8u : 0u) |
                 (cc.x > 0.f ? 16u : 0u) | (cc.y > 0.f ? 32u : 0u);
    sdtm[d] = m;
  }
  {
    const float4* Bp = (const float4*)(xdbl + ((size_t)bk * RN + RR) * LL);
    const float4* Cp = (const float4*)(xdbl + ((size_t)bk * RN + RR + NN) * LL);
    for (int i = d; i < 256; i += 192) {
      int n = i >> 4, j = i & 15;
      float4 v = Bp[n * 1024 + (t0 >> 2) + j];
      sBf[(4 * j + 0) * 16 + n] = v.x;
      sBf[(4 * j + 1) * 16 + n] = v.y;
      sBf[(4 * j + 2) * 16 + n] = v.z;
      sBf[(4 * j + 3) * 16 + n] = v.w;
      float4 w = Cp[n * 1024 + (t0 >> 2) + j];
      sCf[(4 * j + 0) * 16 + n] = w.x;
      sCf[(4 * j + 1) * 16 + n] = w.y;
      sCf[(4 * j + 2) * 16 + n] = w.z;
      sCf[(4 * j + 3) * 16 + n] = w.w;
    }
  }
  uint32_t w6 = ((const uint32_t*)(ws + OFF_WDB))[k * DN + d];
  float sdv = (ws + OFF_WDB)[768 + k * DN + d];
  float biasd = bd[k * DN + d] + dt_bias[k * DN + d];
  float Dd = Ds[k * DN + d];
  #pragma unroll
  for (int pc = 0; pc < 7; ++pc) {
    float dv = softplusf(biasd + sdv * (float)(RR - 2 * pc));
    sDV[pc * 192 + d] = dv;
    sR[pc * 192 + d] = exp2f(-dv * LOG2E);
  }
  float Araw[16];
  bool fok = true;
  {
    const float* ap = A_logs + (k * DN + d) * NN;
    #pragma unroll
    for (int n = 0; n < NN; ++n) {
      Araw[n] = -expf(ap[n]);
      fok = fok && (fabsf(Araw[n] + (float)(n + 1)) < 1e-3f);
    }
  }
  bool fastpath = (__ballot(fok) == ~0ull);
  float h[16];
  {
    const float* hp = h0buf + (size_t)c * 49152 + (size_t)(bk * DN + d) * 16;
    #pragma unroll
    for (int n = 0; n < NN; n += 4) {
      float4 v = *(const float4*)(hp + n);
      h[n] = v.x; h[n + 1] = v.y; h[n + 2] = v.z; h[n + 3] = v.w;
    }
  }
  float* xbase = xs + ((size_t)bk * DN) * LL;
  const float* up = xbase + (size_t)d * LL + t0;
  float An[16];
  if (!fastpath) {
    #pragma unroll
    for (int n = 0; n < NN; ++n) An[n] = Araw[n] * LOG2E;
  }
  __syncthreads();
  #pragma unroll 1
  for (int seg = 0; seg < 4; ++seg) {
    #pragma unroll 1
    for (int tt = 0; tt < 4; ++tt) {
      float4 u4 = *(const float4*)(up + seg * 16 + 4 * tt);
      #pragma unroll
      for (int q = 0; q < 4; ++q) {
        int t = seg * 16 + 4 * tt + q;
        float uv = (q == 0) ? u4.x : (q == 1) ? u4.y : (q == 2) ? u4.z : u4.w;
        int pc = (int)__popc(sdtm[t] ^ w6);
        float dv = sDV[pc * 192 + d];
        float du = dv * uv;
        float yv = Dd * uv;
        if (fastpath) {
          float rr = sR[pc * 192 + d];
          float a[16];
          rpowers(rr, a);
          #pragma unroll
          for (int g = 0; g < 4; ++g) {
            float4 bv = sB4[t * 4 + g];
            float4 cv = sC4[t * 4 + g];
            h[4 * g + 0] = a[4 * g + 0] * h[4 * g + 0] + du * bv.x;
            h[4 * g + 1] = a[4 * g + 1] * h[4 * g + 1] + du * bv.y;
            h[4 * g + 2] = a[4 * g + 2] * h[4 * g + 2] + du * bv.z;
            h[4 * g + 3] = a[4 * g + 3] * h[4 * g + 3] + du * bv.w;
            yv += cv.x * h[4 * g + 0];
            yv += cv.y * h[4 * g + 1];
            yv += cv.z * h[4 * g + 2];
            yv += cv.w * h[4 * g + 3];
          }
        } else {
          #pragma unroll
          for (int g = 0; g < 4; ++g) {
            float4 bv = sB4[t * 4 + g];
            float4 cv = sC4[t * 4 + g];
            float a0 = exp2f(dv * An[4 * g + 0]);
            float a1 = exp2f(dv * An[4 * g + 1]);
            float a2 = exp2f(dv * An[4 * g + 2]);
            float a3 = exp2f(dv * An[4 * g + 3]);
            h[4 * g + 0] = a0 * h[4 * g + 0] + du * bv.x;
            h[4 * g + 1] = a1 * h[4 * g + 1] + du * bv.y;
            h[4 * g + 2] = a2 * h[4 * g + 2] + du * bv.z;
            h[4 * g + 3] = a3 * h[4 * g + 3] + du * bv.w;
            yv += cv.x * h[4 * g + 0];
            yv += cv.y * h[4 * g + 1];
            yv += cv.z * h[4 * g + 2];
            yv += cv.w * h[4 * g + 3];
          }
        }
        ytile[d * 17 + (t & 15)] = yv;
      }
    }
    __syncthreads();
    for (int i = d; i < 3072; i += 192) {
      int dd = i >> 4, tq = i & 15;
      xbase[(size_t)dd * LL + t0 + seg * 16 + tq] = ytile[dd * 17 + tq];
    }
    __syncthreads();
  }
}

// ---------------- combine 4 directions ----------------
__global__ __launch_bounds__(256) void k_comb(const float* __restrict__ xs,
                                              float* __restrict__ y) {
  __shared__ float tA[64][65], tB[64][65];
  int bd = blockIdx.x;
  int b = bd / DN, d = bd % DN;
  const float* p0 = xs + ((size_t)((b * 4 + 0) * DN + d)) * LL;
  const float* p1 = xs + ((size_t)((b * 4 + 1) * DN + d)) * LL;
  const float* p2 = xs + ((size_t)((b * 4 + 2) * DN + d)) * LL;
  const float* p3 = xs + ((size_t)((b * 4 + 3) * DN + d)) * LL;
  for (int i = threadIdx.x; i < LL; i += 256) {
    tA[i >> 6][i & 63] = p1[i];
    tB[i >> 6][i & 63] = p3[i];
  }
  __syncthreads();
  float* yo = y + (size_t)bd * LL;
  for (int l = threadIdx.x; l < LL; l += 256) {
    float v = p0[l] + tA[l & 63][l >> 6] + p2[4095 - l] +
              tB[63 - (l & 63)][63 - (l >> 6)];
    yo[l] = v;
  }
}

// ---------------- LayerNorm + silu(z) gate + output bilinear (fused) ----------------
__global__ __launch_bounds__(256) void k_ln_out(
    const float* __restrict__ y, const float* __restrict__ zs,
    const float* __restrict__ ln_w, const float* __restrict__ ln_b,
    const float* __restrict__ ws, const float* __restrict__ b_out,
    const float* __restrict__ s_out, float* __restrict__ out) {
  __shared__ float ty[64 * 193];
  __shared__ float ps[256];
  __shared__ float smu[64], srs[64];
  __shared__ float slw[DN], slb[DN];
  __shared__ uint32_t ybits[64 * 6];
  __shared__ uint32_t swo[96 * 6];
  __shared__ float sb[96], ssc[96];
  int b = blockIdx.x >> 6;
  int l0 = (blockIdx.x & 63) << 6;
  const float* yp = y + (size_t)b * DN * LL + l0;
  if (threadIdx.x < DN) {
    slw[threadIdx.x] = ln_w[threadIdx.x];
    slb[threadIdx.x] = ln_b[threadIdx.x];
  }
  for (int i = threadIdx.x; i < 96 * 6; i += 256) swo[i] = ((const uint32_t*)(ws + OFF_WOUTB))[i];
  if (threadIdx.x < 96) {
    sb[threadIdx.x] = b_out[threadIdx.x];
    ssc[threadIdx.x] = s_out[threadIdx.x];
  }
  for (int i = threadIdx.x; i < 64 * DN; i += 256) {
    int d2 = i >> 6, lc = i & 63;
    ty[lc * 193 + d2] = yp[(size_t)d2 * LL + lc];
  }
  __syncthreads();
  int lc = threadIdx.x & 63, part = threadIdx.x >> 6;
  float s = 0.f;
  for (int d = part * 48; d < part * 48 + 48; ++d) s += ty[lc * 193 + d];
  ps[threadIdx.x] = s;
  __syncthreads();
  if (threadIdx.x < 64)
    smu[threadIdx.x] = (ps[threadIdx.x] + ps[threadIdx.x + 64] +
                        ps[threadIdx.x + 128] + ps[threadIdx.x + 192]) / (float)DN;
  __syncthreads();
  float mu = smu[lc];
  float q = 0.f;
  for (int d = part * 48; d < part * 48 + 48; ++d) {
    float v = ty[lc * 193 + d] - mu; q += v * v;
  }
  ps[threadIdx.x] = q;
  __syncthreads();
  if (threadIdx.x < 64) {
    float var = (ps[threadIdx.x] + ps[threadIdx.x + 64] +
                 ps[threadIdx.x + 128] + ps[threadIdx.x + 192]) / (float)DN;
    srs[threadIdx.x] = rsqrtf(var + 1e-5f);
  }
  __syncthreads();
  for (int item = threadIdx.x; item < 64 * 6; item += 256) {
    int lc2 = item / 6, wd = item % 6;
    float mu2 = smu[lc2], rs2 = srs[lc2];
    const float* zb = zs + (size_t)(b * LL + l0 + lc2) * DN + wd * 32;
    uint32_t wv = 0;
    #pragma unroll
    for (int i = 0; i < 32; ++i) {
      int d = wd * 32 + i;
      float ln = (ty[lc2 * 193 + d] - mu2) * rs2 * slw[d] + slb[d];
      wv |= ((ln * zb[i] > 0.f) ? 1u : 0u) << i;
    }
    ybits[lc2 * 6 + wd] = wv;
  }
  __syncthreads();
  float* op = out + (size_t)(b * LL + l0) * DM;
  for (int oi = threadIdx.x; oi < 64 * DM; oi += 256) {
    int pr = oi / DM, m = oi % DM;
    int P = 0;
    #pragma unroll
    for (int j = 0; j < 6; ++j) P += (int)__popc(ybits[pr * 6 + j] ^ swo[m * 6 + j]);
    op[(size_t)pr * DM + m] = sb[m] + ssc[m] * (float)(DN - 2 * P);
  }
}

extern "C" void kernel_launch(void* const* d_in, const int* in_sizes, int n_in,
                              void* d_out, int out_size, void* d_ws, size_t ws_size,
                              hipStream_t stream) {
  const float* x       = (const float*)d_in[0];
  const float* W_in    = (const float*)d_in[1];
  const float* b_in    = (const float*)d_in[2];
  const float* s_in    = (const float*)d_in[3];
  const float* move0_b = (const float*)d_in[4];
  const float* conv_W  = (const float*)d_in[5];
  const float* conv_b  = (const float*)d_in[6];
  const float* rp_b0   = (const float*)d_in[7];
  const float* prelu_a = (const float*)d_in[8];
  const float* rp_b1   = (const float*)d_in[9];
  const float* Wl      = (const float*)d_in[10];
  const float* bl      = (const float*)d_in[11];
  const float* sl      = (const float*)d_in[12];
  const float* Wd      = (const float*)d_in[13];
  const float* bd      = (const float*)d_in[14];
  const float* sd      = (const float*)d_in[15];
  const float* dt_bias = (const float*)d_in[16];
  const float* A_logs  = (const float*)d_in[17];
  const float* Ds      = (const float*)d_in[18];
  const float* ln_w    = (const float*)d_in[19];
  const float* ln_b    = (const float*)d_in[20];
  const float* W_out   = (const float*)d_in[21];
  const float* b_out   = (const float*)d_in[22];
  const float* s_out   = (const float*)d_in[23];
  float* ws  = (float*)d_ws;
  float* out = (float*)d_out;

  hipLaunchKernelGGL(k_prep, dim3(1616), dim3(64), 0, stream,
                     W_in, s_in, W_out, s_out, Wl, sl, Wd, sd, conv_W, ws);
  hipLaunchKernelGGL(k_bilin_in, dim3(1024), dim3(384), 0, stream,
                     x, b_in, s_in, move0_b, ws, ws + OFF_XC, ws + OFF_ZS,
                     (uint32_t*)(ws + OFF_XBP));
  hipLaunchKernelGGL(k_conv, dim3(256), dim3(256), 0, stream,
                     (const uint32_t*)(ws + OFF_XBP), ws + OFF_XC,
                     (const uint32_t*)(ws + OFF_WCS), (const int*)(ws + OFF_WAUX),
                     ws + OFF_WSC, conv_b, rp_b0, prelu_a, rp_b1,
                     ws + OFF_XCONV);
  hipLaunchKernelGGL(k_build_xs, dim3(768), dim3(256), 0, stream,
                     ws + OFF_XCONV, ws + OFF_XS, (uint32_t*)(ws + OFF_PXS));
  hipLaunchKernelGGL(k_xdbl, dim3(256), dim3(256), 0, stream,
                     (const uint32_t*)(ws + OFF_PXS), ws, bl, sl, ws + OFF_XDBL);
  hipLaunchKernelGGL(k_scan_a, dim3(1024), dim3(192), 0, stream,
                     ws + OFF_XS, ws + OFF_XDBL, ws, bd, dt_bias, A_logs,
                     ws + OFF_HEND, ws + OFF_SSUM);
  hipLaunchKernelGGL(k_scan_b, dim3(192), dim3(256), 0, stream,
                     A_logs, ws + OFF_SSUM, ws + OFF_HEND);
  hipLaunchKernelGGL(k_scan_c, dim3(1024), dim3(192), 0, stream,
                     ws + OFF_XS, ws + OFF_XDBL, ws, bd, dt_bias, A_logs, Ds,
                     ws + OFF_HEND);
  hipLaunchKernelGGL(k_comb, dim3(768), dim3(256), 0, stream,
                     ws + OFF_XS, ws + OFF_XC);
  hipLaunchKernelGGL(k_ln_out, dim3(256), dim3(256), 0, stream,
                     ws + OFF_XC, ws + OFF_ZS, ln_w, ln_b, ws, b_out, s_out, out);
}

// Round 16
// 308.711 us; speedup vs baseline: 1.0216x; 1.0216x over previous
//
#include <hip/hip_runtime.h>
#include <math.h>
#include <stdint.h>

// Problem constants
#define BB 4
#define HH 64
#define WW2 64
#define DM 96
#define DN 192
#define KK 4
#define NN 16
#define RR 6
#define LL 4096
#define RN 38   // R + 2N

#define LOG2E 1.4426950408889634f
#define LN2   0.6931471805599453f

// Workspace layout (4-byte units). Peak = 24,923,456 floats = 99.69 MB.
#define OFF_WDB      0           // u32[768] packed Wd sign bits + float[768] sd at +768
#define OFF_WCS      4608        // u32[192*56] packed conv weights
#define OFF_WAUX     15360       // int[192*8] conv border corrections
#define OFF_WSC      16896       // float[192] conv scale
#define OFF_WBIB     17088       // u32[384*3] packed W_in sign bits
#define OFF_WOUTB    18240       // u32[96*6] packed W_out sign bits
#define OFF_WLBB     18816       // u32[152*6] packed Wl sign bits
// shared scratch pool @19728 (393216 words): XBP (bilin->conv), then PXS (build_xs->scans)
#define OFF_XBP      19728       // u32[4*6*4356] conv input bit planes
#define OFF_PXS      19728       // u32[16*24576] packed sign(xs) flat — live through scans
#define OFF_XC       412992      // float[3145728] xp (B,Dn,L); then y [b][d][l] (comb out)
#define OFF_ZS       3558720     // float[3145728] silu(z) (B,L,Dn)
#define OFF_XCONV    6704448     // float[3145728] conv out (B,Dn,L); reused as hend/h0
#define OFF_XS       9850176     // float[12582912] scan input; scan_c overwrites with per-k y
#define OFF_SSUM     22433088    // float[64*3072] chunk delta sums (old xdbl region)
#define OFF_HEND     OFF_XCONV

#define PLANE 4356   // 66*66

__device__ __forceinline__ float fsign(float v) {
  return (v > 0.f) ? 1.f : ((v < 0.f) ? -1.f : 0.f);
}
__device__ __forceinline__ float softplusf(float v) {
  return fmaxf(v, 0.f) + LN2 * log2f(1.f + exp2f(-fabsf(v) * LOG2E));
}
__device__ __forceinline__ float siluf(float v) {
  return v / (1.f + expf(-v));
}
__device__ __forceinline__ float waveAllSum(float s) {
  #pragma unroll
  for (int off = 32; off; off >>= 1) s += __shfl_xor(s, off, 64);
  return s;
}

// ---------------- prep: pack all sign weights + zero conv-plane borders ----------------
__global__ __launch_bounds__(64) void k_prep(
    const float* __restrict__ W_in, const float* __restrict__ s_in,
    const float* __restrict__ W_out, const float* __restrict__ s_out,
    const float* __restrict__ Wl, const float* __restrict__ sl,
    const float* __restrict__ Wd, const float* __restrict__ sd,
    const float* __restrict__ convW, float* __restrict__ ws) {
  __shared__ float srow[1728];
  int r = blockIdx.x, lane = threadIdx.x;
  if (r < 384) {
    const float* row = W_in + r * DM;
    float s = 0.f;
    for (int c = lane; c < DM; c += 64) s += row[c];
    s = waveAllSum(s);
    float mean = s / (float)DM;
    if (lane < 3) {
      uint32_t wv = 0;
      #pragma unroll
      for (int i = 0; i < 32; ++i) wv |= (row[lane * 32 + i] - mean > 0.f ? 1u : 0u) << i;
      ((uint32_t*)(ws + OFF_WBIB))[r * 3 + lane] = wv;
    }
  } else if (r < 480) {
    int m = r - 384;
    const float* row = W_out + m * DN;
    float s = 0.f;
    for (int c = lane; c < DN; c += 64) s += row[c];
    s = waveAllSum(s);
    float mean = s / (float)DN;
    if (lane < 6) {
      uint32_t wv = 0;
      #pragma unroll
      for (int i = 0; i < 32; ++i) wv |= (row[lane * 32 + i] - mean > 0.f ? 1u : 0u) << i;
      ((uint32_t*)(ws + OFF_WOUTB))[m * 6 + lane] = wv;
    }
  } else if (r < 632) {
    int idx = r - 480;
    const float* row = Wl + idx * DN;
    float s = 0.f;
    for (int c = lane; c < DN; c += 64) s += row[c];
    s = waveAllSum(s);
    float mean = s / (float)DN;
    if (lane < 6) {
      uint32_t wv = 0;
      #pragma unroll
      for (int i = 0; i < 32; ++i) wv |= (row[lane * 32 + i] - mean > 0.f ? 1u : 0u) << i;
      ((uint32_t*)(ws + OFF_WLBB))[idx * 6 + lane] = wv;
    }
  } else if (r < 1400) {
    int idx = r - 632;
    const float* row = Wd + idx * RR;
    float s = (lane < RR) ? row[lane] : 0.f;
    s = waveAllSum(s);
    float mean = s / (float)RR;
    unsigned long long mb = __ballot((lane < RR) && (row[lane] - mean > 0.f));
    if (lane == 0) {
      ((uint32_t*)(ws + OFF_WDB))[idx] = (uint32_t)mb & 0x3Fu;
      (ws + OFF_WDB)[768 + idx] = sd[idx];
    }
  } else if (r < 1592) {
    int o = r - 1400;
    const float* row = convW + o * 1728;
    float s = 0.f;
    for (int j = lane; j < 1728; j += 64) {
      float v = row[j];
      srow[j] = v;
      s += fabsf(v);
    }
    s = waveAllSum(s);
    __syncthreads();
    float sc = s / 1728.f;
    uint32_t* wb = (uint32_t*)(ws + OFF_WCS);
    int* aux = (int*)(ws + OFF_WAUX);
    float* scf = ws + OFF_WSC;
    uint32_t word = 0;
    if (lane < 54) {
      int cw = lane / 9, tap = lane % 9;
      #pragma unroll
      for (int i = 0; i < 32; ++i)
        word |= (srow[(cw * 32 + i) * 9 + tap] > 0.f ? 1u : 0u) << i;
      wb[o * 56 + lane] = word;
    } else if (lane < 56) {
      wb[o * 56 + lane] = 0u;
    }
    int pc = (lane < 54) ? 2 * (int)__popc(word) - 32 : 0;
    int tapid = lane % 9;
    int wst = 0;
    #pragma unroll
    for (int cw = 0; cw < 6; ++cw) wst += __shfl(pc, cw * 9 + tapid, 64);
    int w_t[9];
    #pragma unroll
    for (int t9 = 0; t9 < 9; ++t9) w_t[t9] = __shfl(wst, t9, 64);
    if (lane == 0) {
      aux[o * 8 + 0] = w_t[0] + w_t[3] + w_t[6];
      aux[o * 8 + 1] = w_t[2] + w_t[5] + w_t[8];
      aux[o * 8 + 2] = w_t[0] + w_t[1] + w_t[2];
      aux[o * 8 + 3] = w_t[6] + w_t[7] + w_t[8];
      aux[o * 8 + 4] = w_t[0];
      aux[o * 8 + 5] = w_t[2];
      aux[o * 8 + 6] = w_t[6];
      aux[o * 8 + 7] = w_t[8];
      scf[o] = sc;
    }
  } else {
    // zero the border of one conv bit-plane (24 planes)
    int p = r - 1592;
    uint32_t* plane = (uint32_t*)(ws + OFF_XBP) + (size_t)p * PLANE;
    for (int i = lane; i < 66; i += 64) {
      plane[i] = 0u;
      plane[65 * 66 + i] = 0u;
    }
    for (int i = lane; i < 64; i += 64) {
      plane[(i + 1) * 66] = 0u;
      plane[(i + 1) * 66 + 65] = 0u;
    }
  }
}

// ---------------- input bilinear via XOR-popcount + fused conv-input bit-pack ----------------
__global__ __launch_bounds__(384) void k_bilin_in(
    const float* __restrict__ x, const float* __restrict__ b_in,
    const float* __restrict__ s_in, const float* __restrict__ move0,
    const float* __restrict__ ws, float* __restrict__ xc, float* __restrict__ zs,
    uint32_t* __restrict__ xb) {
  __shared__ uint32_t spx[16 * 3];
  __shared__ float sxz[384 * 17];
  __shared__ float smv[DN];
  int p0 = blockIdx.x * 16;
  if (threadIdx.x < 48) {
    int pix = threadIdx.x / 3, wd = threadIdx.x % 3;
    const float* base = x + (size_t)(p0 + pix) * DM + wd * 32;
    uint32_t wv = 0;
    #pragma unroll
    for (int i = 0; i < 32; ++i) wv |= (base[i] > 0.f ? 1u : 0u) << i;
    spx[pix * 3 + wd] = wv;
  }
  if (threadIdx.x < DN) smv[threadIdx.x] = move0[threadIdx.x];
  __syncthreads();
  int o = threadIdx.x;
  uint32_t w0, w1, w2;
  {
    const uint32_t* wb = (const uint32_t*)(ws + OFF_WBIB) + o * 3;
    w0 = wb[0]; w1 = wb[1]; w2 = wb[2];
  }
  float bias = b_in[o], sc = s_in[o];
  #pragma unroll
  for (int pix = 0; pix < 16; ++pix) {
    int P = (int)__popc(spx[pix * 3 + 0] ^ w0) + (int)__popc(spx[pix * 3 + 1] ^ w1) +
            (int)__popc(spx[pix * 3 + 2] ^ w2);
    sxz[o * 17 + pix] = bias + sc * (float)(DM - 2 * P);
  }
  __syncthreads();
  int b = p0 >> 12, l0 = p0 & 4095;
  for (int f = threadIdx.x; f < DN * 16; f += 384) {
    int od = f >> 4, pix = f & 15;
    xc[((size_t)(b * DN + od)) * LL + l0 + pix] = sxz[od * 17 + pix];
  }
  for (int f = threadIdx.x; f < DN * 16; f += 384) {
    int pix = f / DN, oz = f - pix * DN;
    zs[(size_t)(p0 + pix) * DN + oz] = siluf(sxz[(DN + oz) * 17 + pix]);
  }
  if (threadIdx.x < 96) {
    int pix = threadIdx.x / 6, cw = threadIdx.x % 6;
    uint32_t wv = 0;
    #pragma unroll
    for (int i = 0; i < 32; ++i) {
      int dch = cw * 32 + i;
      wv |= ((sxz[dch * 17 + pix] + smv[dch] > 0.f) ? 1u : 0u) << i;
    }
    int l = l0 + pix, h = l >> 6, w = l & 63;
    uint32_t* plane = xb + (size_t)(b * 6 + cw) * PLANE;
    plane[(h + 1) * 66 + 1 + w] = wv;
  }
}

// ---------------- XNOR-popcount binary 3x3 conv + RPReLU + residual + SiLU ----------------
__global__ __launch_bounds__(256) void k_conv(
    const uint32_t* __restrict__ xb, const float* __restrict__ xc,
    const uint32_t* __restrict__ wbits, const int* __restrict__ aux,
    const float* __restrict__ scf, const float* __restrict__ conv_b,
    const float* __restrict__ rp_b0, const float* __restrict__ prelu_a,
    const float* __restrict__ rp_b1, float* __restrict__ xconv) {
  int og = blockIdx.x & 3;
  int stripe = (blockIdx.x >> 2) & 15;
  int b = blockIdx.x >> 6;
  int w = threadIdx.x & 63, r = threadIdx.x >> 6;
  int h = stripe * 4 + r;

  __shared__ uint32_t swb[48 * 56];
  __shared__ int saux[48 * 8];
  __shared__ float sconst[48 * 4];
  for (int i = threadIdx.x; i < 48 * 56; i += 256) swb[i] = wbits[og * (48 * 56) + i];
  for (int i = threadIdx.x; i < 48 * 8; i += 256) saux[i] = aux[og * (48 * 8) + i];
  if (threadIdx.x < 48) {
    int o = og * 48 + threadIdx.x;
    sconst[threadIdx.x * 4 + 0] = scf[o];
    sconst[threadIdx.x * 4 + 1] = conv_b[o] + rp_b0[o];
    sconst[threadIdx.x * 4 + 2] = prelu_a[o];
    sconst[threadIdx.x * 4 + 3] = rp_b1[o];
  }

  uint32_t xw[6][9];
  const uint32_t* xpb = xb + (size_t)b * 6 * PLANE;
  #pragma unroll
  for (int cw = 0; cw < 6; ++cw) {
    const uint32_t* plane = xpb + cw * PLANE + (h + 1) * 66 + (w + 1);
    #pragma unroll
    for (int dy = 0; dy < 3; ++dy) {
      #pragma unroll
      for (int dx = 0; dx < 3; ++dx)
        xw[cw][dy * 3 + dx] = plane[(dy - 1) * 66 + (dx - 1)];
    }
  }
  bool isL = (w == 0), isR = (w == 63);
  bool isT = (h == 0), isB = (h == 63);
  const float* xcp = xc + ((size_t)(b * DN + og * 48)) * LL + h * 64 + w;
  float* xop = xconv + ((size_t)(b * DN + og * 48)) * LL + h * 64 + w;
  __syncthreads();

  #pragma unroll 1
  for (int oc = 0; oc < 48; ++oc) {
    const uint32_t* wp = &swb[oc * 56];
    int P = 0;
    #pragma unroll
    for (int cw = 0; cw < 6; ++cw) {
      int pp = 0;
      #pragma unroll
      for (int t = 0; t < 9; ++t) pp += (int)__popc(wp[cw * 9 + t] ^ xw[cw][t]);
      P += pp;
    }
    int corr = isL ? saux[oc * 8 + 0] : (isR ? saux[oc * 8 + 1] : 0);
    if (isT) {
      corr += saux[oc * 8 + 2];
      if (isL) corr -= saux[oc * 8 + 4];
      if (isR) corr -= saux[oc * 8 + 5];
    }
    if (isB) {
      corr += saux[oc * 8 + 3];
      if (isL) corr -= saux[oc * 8 + 6];
      if (isR) corr -= saux[oc * 8 + 7];
    }
    float acc = sconst[oc * 4 + 0] * (float)(1728 - 2 * P + corr);
    float t = acc + sconst[oc * 4 + 1];
    t = (t >= 0.f) ? t : sconst[oc * 4 + 2] * t;
    t += sconst[oc * 4 + 3] + *xcp;
    *xop = siluf(t);
    xcp += LL; xop += LL;
  }
}

// ---------------- build xs: LDS-tiled 4-direction expand + ballot bit-pack ----------------
__global__ __launch_bounds__(256) void k_build_xs(const float* __restrict__ xconv,
                                                  float* __restrict__ xs,
                                                  uint32_t* __restrict__ pxs) {
  __shared__ float tile[64][65];
  int bd = blockIdx.x;
  int b = bd / DN, d = bd % DN;
  const float* img = xconv + (size_t)bd * LL;
  for (int i = threadIdx.x; i < LL; i += 256)
    tile[i >> 6][i & 63] = img[i];
  __syncthreads();
  int lane = threadIdx.x & 63;
  #pragma unroll
  for (int k = 0; k < 4; ++k) {
    size_t base = ((size_t)((b * KK + k) * DN + d)) * LL;
    for (int j = threadIdx.x; j < LL; j += 256) {
      float v;
      if (k == 0)      v = tile[j >> 6][j & 63];
      else if (k == 1) v = tile[j & 63][j >> 6];
      else if (k == 2) { int t2 = 4095 - j; v = tile[t2 >> 6][t2 & 63]; }
      else             { int t2 = 4095 - j; v = tile[t2 & 63][t2 >> 6]; }
      xs[base + j] = v;
      unsigned long long m = __ballot(v > 0.f);
      if (lane == 0)       pxs[(base + j) >> 5] = (uint32_t)m;
      else if (lane == 32) pxs[(base + j) >> 5] = (uint32_t)(m >> 32);
    }
  }
}

// power ladder: a[n] = r^(n+1), 14 mults, depth 4
__device__ __forceinline__ void rpowers(float r, float* a) {
  float r2 = r * r, r3 = r2 * r, r4 = r2 * r2, r8 = r4 * r4;
  a[0] = r;       a[1] = r2;      a[2] = r3;      a[3] = r4;
  a[4] = r4 * r;  a[5] = r4 * r2; a[6] = r4 * r3; a[7] = r8;
  a[8] = r8 * r;  a[9] = r8 * r2; a[10] = r8 * r3; a[11] = r8 * r4;
  a[12] = r8 * a[4]; a[13] = r8 * a[5]; a[14] = r8 * a[6]; a[15] = r8 * r8;
}

// ---------------- scan pass A: B/dt computed from pxs (no xdbl) ----------------
__global__ __launch_bounds__(192) void k_scan_a(
    const float* __restrict__ xs, const uint32_t* __restrict__ pxs,
    const float* __restrict__ ws, const float* __restrict__ bl,
    const float* __restrict__ sl, const float* __restrict__ bd,
    const float* __restrict__ dt_bias, const float* __restrict__ A_logs,
    float* __restrict__ hend, float* __restrict__ Ssum) {
  int c = blockIdx.x & 63;
  int bk = blockIdx.x >> 6;
  int k = bk & 3;
  int d = threadIdx.x;
  int t0 = c << 6;
  __shared__ uint32_t sdtm[64];
  __shared__ uint32_t spxr[64 * 6];     // pxs rows t0..t0+63
  __shared__ uint32_t swl[RN * 6];
  __shared__ float sblv[RN], sslv[RN];
  __shared__ float4 sB4[256];
  __shared__ float sDV[7 * 192], sR[7 * 192];
  float* sBf = (float*)sB4;
  const uint32_t* ppx = pxs + (size_t)bk * 24576;
  for (int i = d; i < 384; i += 192) spxr[i] = ppx[t0 * 6 + i];
  for (int i = d; i < RN * 6; i += 192) swl[i] = ((const uint32_t*)(ws + OFF_WLBB))[k * RN * 6 + i];
  if (d < RN) {
    sblv[d] = bl[k * RN + d];
    sslv[d] = sl[k * RN + d];
  }
  __syncthreads();
  // dt sign masks via raw-reshape mapping f = t*6+r -> row f>>12, col f&4095
  if (d < 64) {
    uint32_t m = 0;
    int fbase = (t0 + d) * 6;
    #pragma unroll
    for (int r = 0; r < 6; ++r) {
      int f = fbase + r;
      int o = f >> 12, l = f & 4095;
      const uint32_t* prow = ppx + l * 6;
      int P = 0;
      #pragma unroll
      for (int j = 0; j < 6; ++j) P += (int)__popc(prow[j] ^ swl[o * 6 + j]);
      float val = sblv[o] + sslv[o] * (float)(DN - 2 * P);
      m |= (val > 0.f ? 1u : 0u) << r;
    }
    sdtm[d] = m;
  }
  // B values: rows RR..RR+15
  for (int i = d; i < 1024; i += 192) {
    int t = i >> 4, n = i & 15;
    int o = RR + n;
    int P = 0;
    #pragma unroll
    for (int j = 0; j < 6; ++j) P += (int)__popc(spxr[t * 6 + j] ^ swl[o * 6 + j]);
    sBf[t * 16 + n] = sblv[o] + sslv[o] * (float)(DN - 2 * P);
  }
  uint32_t w6 = ((const uint32_t*)(ws + OFF_WDB))[k * DN + d];
  float sdv = (ws + OFF_WDB)[768 + k * DN + d];
  float biasd = bd[k * DN + d] + dt_bias[k * DN + d];
  #pragma unroll
  for (int pc = 0; pc < 7; ++pc) {
    float dv = softplusf(biasd + sdv * (float)(RR - 2 * pc));
    sDV[pc * 192 + d] = dv;
    sR[pc * 192 + d] = exp2f(-dv * LOG2E);
  }
  float Araw[16];
  bool fok = true;
  {
    const float* ap = A_logs + (k * DN + d) * NN;
    #pragma unroll
    for (int n = 0; n < NN; ++n) {
      Araw[n] = -expf(ap[n]);
      fok = fok && (fabsf(Araw[n] + (float)(n + 1)) < 1e-3f);
    }
  }
  bool fastpath = (__ballot(fok) == ~0ull);
  float h[16];
  #pragma unroll
  for (int n = 0; n < NN; ++n) h[n] = 0.f;
  float S = 0.f;
  const float* up = xs + ((size_t)bk * DN + d) * LL + t0;
  __syncthreads();
  if (fastpath) {
    #pragma unroll 1
    for (int tt = 0; tt < 16; ++tt) {
      float4 u4 = *(const float4*)(up + 4 * tt);
      #pragma unroll
      for (int q = 0; q < 4; ++q) {
        int t = 4 * tt + q;
        float uv = (q == 0) ? u4.x : (q == 1) ? u4.y : (q == 2) ? u4.z : u4.w;
        int pc = (int)__popc(sdtm[t] ^ w6);
        float dv = sDV[pc * 192 + d];
        float rr = sR[pc * 192 + d];
        S += dv;
        float du = dv * uv;
        float a[16];
        rpowers(rr, a);
        #pragma unroll
        for (int g = 0; g < 4; ++g) {
          float4 bv = sB4[t * 4 + g];
          h[4 * g + 0] = a[4 * g + 0] * h[4 * g + 0] + du * bv.x;
          h[4 * g + 1] = a[4 * g + 1] * h[4 * g + 1] + du * bv.y;
          h[4 * g + 2] = a[4 * g + 2] * h[4 * g + 2] + du * bv.z;
          h[4 * g + 3] = a[4 * g + 3] * h[4 * g + 3] + du * bv.w;
        }
      }
    }
  } else {
    float An[16];
    #pragma unroll
    for (int n = 0; n < NN; ++n) An[n] = Araw[n] * LOG2E;
    #pragma unroll 1
    for (int tt = 0; tt < 16; ++tt) {
      float4 u4 = *(const float4*)(up + 4 * tt);
      #pragma unroll
      for (int q = 0; q < 4; ++q) {
        int t = 4 * tt + q;
        float uv = (q == 0) ? u4.x : (q == 1) ? u4.y : (q == 2) ? u4.z : u4.w;
        int pc = (int)__popc(sdtm[t] ^ w6);
        float dv = sDV[pc * 192 + d];
        S += dv;
        float du = dv * uv;
        #pragma unroll
        for (int g = 0; g < 4; ++g) {
          float4 bv = sB4[t * 4 + g];
          float a0 = exp2f(dv * An[4 * g + 0]);
          float a1 = exp2f(dv * An[4 * g + 1]);
          float a2 = exp2f(dv * An[4 * g + 2]);
          float a3 = exp2f(dv * An[4 * g + 3]);
          h[4 * g + 0] = a0 * h[4 * g + 0] + du * bv.x;
          h[4 * g + 1] = a1 * h[4 * g + 1] + du * bv.y;
          h[4 * g + 2] = a2 * h[4 * g + 2] + du * bv.z;
          h[4 * g + 3] = a3 * h[4 * g + 3] + du * bv.w;
        }
      }
    }
  }
  float* hp = hend + (size_t)c * 49152 + (size_t)(bk * DN + d) * 16;
  #pragma unroll
  for (int n = 0; n < NN; n += 4)
    *(float4*)(hp + n) = make_float4(h[n], h[n + 1], h[n + 2], h[n + 3]);
  Ssum[c * 3072 + bk * DN + d] = S;
}

// ---------------- scan pass B ----------------
__global__ __launch_bounds__(256) void k_scan_b(
    const float* __restrict__ A_logs, const float* __restrict__ Ssum,
    float* __restrict__ hend) {
  int tid = blockIdx.x * 256 + threadIdx.x;
  int bkd = tid >> 4, n = tid & 15;
  int bk = bkd / DN, d = bkd - bk * DN;
  int k = bk & 3;
  float An2 = -expf(A_logs[(k * DN + d) * NN + n]) * LOG2E;
  float h = 0.f;
  float Sc = Ssum[bkd];
  float he = hend[tid];
  #pragma unroll 1
  for (int c = 0; c < 64; ++c) {
    float Sn = 0.f, hn = 0.f;
    if (c < 63) {
      Sn = Ssum[(c + 1) * 3072 + bkd];
      hn = hend[(size_t)(c + 1) * 49152 + tid];
    }
    hend[(size_t)c * 49152 + tid] = h;
    h = exp2f(An2 * Sc) * h + he;
    Sc = Sn; he = hn;
  }
}

// ---------------- scan pass C: B/C/dt from pxs, y in place into xs ----------------
__global__ __launch_bounds__(192) void k_scan_c(
    float* __restrict__ xs, const uint32_t* __restrict__ pxs,
    const float* __restrict__ ws, const float* __restrict__ bl,
    const float* __restrict__ sl, const float* __restrict__ bd,
    const float* __restrict__ dt_bias, const float* __restrict__ A_logs,
    const float* __restrict__ Ds, const float* __restrict__ h0buf) {
  int c = blockIdx.x & 63;
  int bk = blockIdx.x >> 6;
  int k = bk & 3;
  int d = threadIdx.x;
  int t0 = c << 6;
  __shared__ uint32_t sdtm[64];
  __shared__ uint32_t spxr[64 * 6];
  __shared__ uint32_t swl[RN * 6];
  __shared__ float sblv[RN], sslv[RN];
  __shared__ float4 sB4[256];
  __shared__ float4 sC4[256];
  __shared__ float sDV[7 * 192], sR[7 * 192];
  __shared__ float ytile[192 * 17];
  float* sBf = (float*)sB4;
  float* sCf = (float*)sC4;
  const uint32_t* ppx = pxs + (size_t)bk * 24576;
  for (int i = d; i < 384; i += 192) spxr[i] = ppx[t0 * 6 + i];
  for (int i = d; i < RN * 6; i += 192) swl[i] = ((const uint32_t*)(ws + OFF_WLBB))[k * RN * 6 + i];
  if (d < RN) {
    sblv[d] = bl[k * RN + d];
    sslv[d] = sl[k * RN + d];
  }
  __syncthreads();
  if (d < 64) {
    uint32_t m = 0;
    int fbase = (t0 + d) * 6;
    #pragma unroll
    for (int r = 0; r < 6; ++r) {
      int f = fbase + r;
      int o = f >> 12, l = f & 4095;
      const uint32_t* prow = ppx + l * 6;
      int P = 0;
      #pragma unroll
      for (int j = 0; j < 6; ++j) P += (int)__popc(prow[j] ^ swl[o * 6 + j]);
      float val = sblv[o] + sslv[o] * (float)(DN - 2 * P);
      m |= (val > 0.f ? 1u : 0u) << r;
    }
    sdtm[d] = m;
  }
  // B and C values: rows RR..RR+31
  for (int i = d; i < 2048; i += 192) {
    int t = i >> 5, nn = i & 31;
    int o = RR + nn;
    int P = 0;
    #pragma unroll
    for (int j = 0; j < 6; ++j) P += (int)__popc(spxr[t * 6 + j] ^ swl[o * 6 + j]);
    float val = sblv[o] + sslv[o] * (float)(DN - 2 * P);
    if (nn < 16) sBf[t * 16 + nn] = val;
    else         sCf[t * 16 + (nn - 16)] = val;
  }
  uint32_t w6 = ((const uint32_t*)(ws + OFF_WDB))[k * DN + d];
  float sdv = (ws + OFF_WDB)[768 + k * DN + d];
  float biasd = bd[k * DN + d] + dt_bias[k * DN + d];
  float Dd = Ds[k * DN + d];
  #pragma unroll
  for (int pc = 0; pc < 7; ++pc) {
    float dv = softplusf(biasd + sdv * (float)(RR - 2 * pc));
    sDV[pc * 192 + d] = dv;
    sR[pc * 192 + d] = exp2f(-dv * LOG2E);
  }
  float Araw[16];
  bool fok = true;
  {
    const float* ap = A_logs + (k * DN + d) * NN;
    #pragma unroll
    for (int n = 0; n < NN; ++n) {
      Araw[n] = -expf(ap[n]);
      fok = fok && (fabsf(Araw[n] + (float)(n + 1)) < 1e-3f);
    }
  }
  bool fastpath = (__ballot(fok) == ~0ull);
  float h[16];
  {
    const float* hp = h0buf + (size_t)c * 49152 + (size_t)(bk * DN + d) * 16;
    #pragma unroll
    for (int n = 0; n < NN; n += 4) {
      float4 v = *(const float4*)(hp + n);
      h[n] = v.x; h[n + 1] = v.y; h[n + 2] = v.z; h[n + 3] = v.w;
    }
  }
  float* xbase = xs + ((size_t)bk * DN) * LL;
  const float* up = xbase + (size_t)d * LL + t0;
  float An[16];
  if (!fastpath) {
    #pragma unroll
    for (int n = 0; n < NN; ++n) An[n] = Araw[n] * LOG2E;
  }
  __syncthreads();
  #pragma unroll 1
  for (int seg = 0; seg < 4; ++seg) {
    #pragma unroll 1
    for (int tt = 0; tt < 4; ++tt) {
      float4 u4 = *(const float4*)(up + seg * 16 + 4 * tt);
      #pragma unroll
      for (int q = 0; q < 4; ++q) {
        int t = seg * 16 + 4 * tt + q;
        float uv = (q == 0) ? u4.x : (q == 1) ? u4.y : (q == 2) ? u4.z : u4.w;
        int pc = (int)__popc(sdtm[t] ^ w6);
        float dv = sDV[pc * 192 + d];
        float du = dv * uv;
        float yv = Dd * uv;
        if (fastpath) {
          float rr = sR[pc * 192 + d];
          float a[16];
          rpowers(rr, a);
          #pragma unroll
          for (int g = 0; g < 4; ++g) {
            float4 bv = sB4[t * 4 + g];
            float4 cv = sC4[t * 4 + g];
            h[4 * g + 0] = a[4 * g + 0] * h[4 * g + 0] + du * bv.x;
            h[4 * g + 1] = a[4 * g + 1] * h[4 * g + 1] + du * bv.y;
            h[4 * g + 2] = a[4 * g + 2] * h[4 * g + 2] + du * bv.z;
            h[4 * g + 3] = a[4 * g + 3] * h[4 * g + 3] + du * bv.w;
            yv += cv.x * h[4 * g + 0];
            yv += cv.y * h[4 * g + 1];
            yv += cv.z * h[4 * g + 2];
            yv += cv.w * h[4 * g + 3];
          }
        } else {
          #pragma unroll
          for (int g = 0; g < 4; ++g) {
            float4 bv = sB4[t * 4 + g];
            float4 cv = sC4[t * 4 + g];
            float a0 = exp2f(dv * An[4 * g + 0]);
            float a1 = exp2f(dv * An[4 * g + 1]);
            float a2 = exp2f(dv * An[4 * g + 2]);
            float a3 = exp2f(dv * An[4 * g + 3]);
            h[4 * g + 0] = a0 * h[4 * g + 0] + du * bv.x;
            h[4 * g + 1] = a1 * h[4 * g + 1] + du * bv.y;
            h[4 * g + 2] = a2 * h[4 * g + 2] + du * bv.z;
            h[4 * g + 3] = a3 * h[4 * g + 3] + du * bv.w;
            yv += cv.x * h[4 * g + 0];
            yv += cv.y * h[4 * g + 1];
            yv += cv.z * h[4 * g + 2];
            yv += cv.w * h[4 * g + 3];
          }
        }
        ytile[d * 17 + (t & 15)] = yv;
      }
    }
    __syncthreads();
    for (int i = d; i < 3072; i += 192) {
      int dd = i >> 4, tq = i & 15;
      xbase[(size_t)dd * LL + t0 + seg * 16 + tq] = ytile[dd * 17 + tq];
    }
    __syncthreads();
  }
}

// ---------------- combine 4 directions ----------------
__global__ __launch_bounds__(256) void k_comb(const float* __restrict__ xs,
                                              float* __restrict__ y) {
  __shared__ float tA[64][65], tB[64][65];
  int bd = blockIdx.x;
  int b = bd / DN, d = bd % DN;
  const float* p0 = xs + ((size_t)((b * 4 + 0) * DN + d)) * LL;
  const float* p1 = xs + ((size_t)((b * 4 + 1) * DN + d)) * LL;
  const float* p2 = xs + ((size_t)((b * 4 + 2) * DN + d)) * LL;
  const float* p3 = xs + ((size_t)((b * 4 + 3) * DN + d)) * LL;
  for (int i = threadIdx.x; i < LL; i += 256) {
    tA[i >> 6][i & 63] = p1[i];
    tB[i >> 6][i & 63] = p3[i];
  }
  __syncthreads();
  float* yo = y + (size_t)bd * LL;
  for (int l = threadIdx.x; l < LL; l += 256) {
    float v = p0[l] + tA[l & 63][l >> 6] + p2[4095 - l] +
              tB[63 - (l & 63)][63 - (l >> 6)];
    yo[l] = v;
  }
}

// ---------------- LayerNorm + silu(z) gate + output bilinear (fused) ----------------
__global__ __launch_bounds__(256) void k_ln_out(
    const float* __restrict__ y, const float* __restrict__ zs,
    const float* __restrict__ ln_w, const float* __restrict__ ln_b,
    const float* __restrict__ ws, const float* __restrict__ b_out,
    const float* __restrict__ s_out, float* __restrict__ out) {
  __shared__ float ty[64 * 193];
  __shared__ float ps[256];
  __shared__ float smu[64], srs[64];
  __shared__ float slw[DN], slb[DN];
  __shared__ uint32_t ybits[64 * 6];
  __shared__ uint32_t swo[96 * 6];
  __shared__ float sb[96], ssc[96];
  int b = blockIdx.x >> 6;
  int l0 = (blockIdx.x & 63) << 6;
  const float* yp = y + (size_t)b * DN * LL + l0;
  if (threadIdx.x < DN) {
    slw[threadIdx.x] = ln_w[threadIdx.x];
    slb[threadIdx.x] = ln_b[threadIdx.x];
  }
  for (int i = threadIdx.x; i < 96 * 6; i += 256) swo[i] = ((const uint32_t*)(ws + OFF_WOUTB))[i];
  if (threadIdx.x < 96) {
    sb[threadIdx.x] = b_out[threadIdx.x];
    ssc[threadIdx.x] = s_out[threadIdx.x];
  }
  for (int i = threadIdx.x; i < 64 * DN; i += 256) {
    int d2 = i >> 6, lc = i & 63;
    ty[lc * 193 + d2] = yp[(size_t)d2 * LL + lc];
  }
  __syncthreads();
  int lc = threadIdx.x & 63, part = threadIdx.x >> 6;
  float s = 0.f;
  for (int d = part * 48; d < part * 48 + 48; ++d) s += ty[lc * 193 + d];
  ps[threadIdx.x] = s;
  __syncthreads();
  if (threadIdx.x < 64)
    smu[threadIdx.x] = (ps[threadIdx.x] + ps[threadIdx.x + 64] +
                        ps[threadIdx.x + 128] + ps[threadIdx.x + 192]) / (float)DN;
  __syncthreads();
  float mu = smu[lc];
  float q = 0.f;
  for (int d = part * 48; d < part * 48 + 48; ++d) {
    float v = ty[lc * 193 + d] - mu; q += v * v;
  }
  ps[threadIdx.x] = q;
  __syncthreads();
  if (threadIdx.x < 64) {
    float var = (ps[threadIdx.x] + ps[threadIdx.x + 64] +
                 ps[threadIdx.x + 128] + ps[threadIdx.x + 192]) / (float)DN;
    srs[threadIdx.x] = rsqrtf(var + 1e-5f);
  }
  __syncthreads();
  for (int item = threadIdx.x; item < 64 * 6; item += 256) {
    int lc2 = item / 6, wd = item % 6;
    float mu2 = smu[lc2], rs2 = srs[lc2];
    const float* zb = zs + (size_t)(b * LL + l0 + lc2) * DN + wd * 32;
    uint32_t wv = 0;
    #pragma unroll
    for (int i = 0; i < 32; ++i) {
      int d = wd * 32 + i;
      float ln = (ty[lc2 * 193 + d] - mu2) * rs2 * slw[d] + slb[d];
      wv |= ((ln * zb[i] > 0.f) ? 1u : 0u) << i;
    }
    ybits[lc2 * 6 + wd] = wv;
  }
  __syncthreads();
  float* op = out + (size_t)(b * LL + l0) * DM;
  for (int oi = threadIdx.x; oi < 64 * DM; oi += 256) {
    int pr = oi / DM, m = oi % DM;
    int P = 0;
    #pragma unroll
    for (int j = 0; j < 6; ++j) P += (int)__popc(ybits[pr * 6 + j] ^ swo[m * 6 + j]);
    op[(size_t)pr * DM + m] = sb[m] + ssc[m] * (float)(DN - 2 * P);
  }
}

extern "C" void kernel_launch(void* const* d_in, const int* in_sizes, int n_in,
                              void* d_out, int out_size, void* d_ws, size_t ws_size,
                              hipStream_t stream) {
  const float* x       = (const float*)d_in[0];
  const float* W_in    = (const float*)d_in[1];
  const float* b_in    = (const float*)d_in[2];
  const float* s_in    = (const float*)d_in[3];
  const float* move0_b = (const float*)d_in[4];
  const float* conv_W  = (const float*)d_in[5];
  const float* conv_b  = (const float*)d_in[6];
  const float* rp_b0   = (const float*)d_in[7];
  const float* prelu_a = (const float*)d_in[8];
  const float* rp_b1   = (const float*)d_in[9];
  const float* Wl      = (const float*)d_in[10];
  const float* bl      = (const float*)d_in[11];
  const float* sl      = (const float*)d_in[12];
  const float* Wd      = (const float*)d_in[13];
  const float* bd      = (const float*)d_in[14];
  const float* sd      = (const float*)d_in[15];
  const float* dt_bias = (const float*)d_in[16];
  const float* A_logs  = (const float*)d_in[17];
  const float* Ds      = (const float*)d_in[18];
  const float* ln_w    = (const float*)d_in[19];
  const float* ln_b    = (const float*)d_in[20];
  const float* W_out   = (const float*)d_in[21];
  const float* b_out   = (const float*)d_in[22];
  const float* s_out   = (const float*)d_in[23];
  float* ws  = (float*)d_ws;
  float* out = (float*)d_out;

  hipLaunchKernelGGL(k_prep, dim3(1616), dim3(64), 0, stream,
                     W_in, s_in, W_out, s_out, Wl, sl, Wd, sd, conv_W, ws);
  hipLaunchKernelGGL(k_bilin_in, dim3(1024), dim3(384), 0, stream,
                     x, b_in, s_in, move0_b, ws, ws + OFF_XC, ws + OFF_ZS,
                     (uint32_t*)(ws + OFF_XBP));
  hipLaunchKernelGGL(k_conv, dim3(256), dim3(256), 0, stream,
                     (const uint32_t*)(ws + OFF_XBP), ws + OFF_XC,
                     (const uint32_t*)(ws + OFF_WCS), (const int*)(ws + OFF_WAUX),
                     ws + OFF_WSC, conv_b, rp_b0, prelu_a, rp_b1,
                     ws + OFF_XCONV);
  hipLaunchKernelGGL(k_build_xs, dim3(768), dim3(256), 0, stream,
                     ws + OFF_XCONV, ws + OFF_XS, (uint32_t*)(ws + OFF_PXS));
  hipLaunchKernelGGL(k_scan_a, dim3(1024), dim3(192), 0, stream,
                     ws + OFF_XS, (const uint32_t*)(ws + OFF_PXS), ws, bl, sl,
                     bd, dt_bias, A_logs, ws + OFF_HEND, ws + OFF_SSUM);
  hipLaunchKernelGGL(k_scan_b, dim3(192), dim3(256), 0, stream,
                     A_logs, ws + OFF_SSUM, ws + OFF_HEND);
  hipLaunchKernelGGL(k_scan_c, dim3(1024), dim3(192), 0, stream,
                     ws + OFF_XS, (const uint32_t*)(ws + OFF_PXS), ws, bl, sl,
                     bd, dt_bias, A_logs, Ds, ws + OFF_HEND);
  hipLaunchKernelGGL(k_comb, dim3(768), dim3(256), 0, stream,
                     ws + OFF_XS, ws + OFF_XC);
  hipLaunchKernelGGL(k_ln_out, dim3(256), dim3(256), 0, stream,
                     ws + OFF_XC, ws + OFF_ZS, ln_w, ln_b, ws, b_out, s_out, out);
}